// Round 1
// baseline (1597.768 us; speedup 1.0000x reference)
//
#include <hip/hip_runtime.h>
#include <math.h>

#define B_V 48
#define B_T 48
#define MQ 32
#define NN 196
#define CC 512
#define HID 102
#define KEEPN 39
#define NKEEP 98
#define TOKS 41

__device__ __forceinline__ float waveSum(float v) {
#pragma unroll
  for (int off = 32; off > 0; off >>= 1) v += __shfl_xor(v, off, 64);
  return v;
}
__device__ __forceinline__ float waveMax(float v) {
#pragma unroll
  for (int off = 32; off > 0; off >>= 1) v = fmaxf(v, __shfl_xor(v, off, 64));
  return v;
}

// ---------------- prep per image: glo, s_im, spatial inverse norms --------
__global__ __launch_bounds__(256) void k_prep_img(const float* __restrict__ img,
                                                  float* __restrict__ ninv,
                                                  float* __restrict__ s_im) {
  int b = blockIdx.x, t = threadIdx.x;
  __shared__ float glo[CC];
  __shared__ float red[256];
  __shared__ float rgS;
  const float* sp = img + ((size_t)b * 197 + 1) * CC;
  float v0 = 0.f, v1 = 0.f;
  for (int n = 0; n < NN; ++n) {
    v0 += sp[(size_t)n * CC + t];
    v1 += sp[(size_t)n * CC + t + 256];
  }
  v0 *= (1.f / NN); v1 *= (1.f / NN);
  glo[t] = v0; glo[t + 256] = v1;
  red[t] = v0 * v0 + v1 * v1;
  __syncthreads();
  for (int s = 128; s > 0; s >>= 1) {
    if (t < s) red[t] += red[t + s];
    __syncthreads();
  }
  if (t == 0) rgS = 1.f / fmaxf(sqrtf(red[0]), 1e-12f);
  __syncthreads();
  float rg = rgS;
  glo[t] *= rg; glo[t + 256] *= rg;
  __syncthreads();
  int w = t >> 6, lane = t & 63;
  for (int n = w; n < NN; n += 4) {
    const float* row = sp + (size_t)n * CC + lane * 8;
    float4 a = *(const float4*)row;
    float4 bq = *(const float4*)(row + 4);
    const float* gl = glo + lane * 8;
    float ss = a.x * a.x + a.y * a.y + a.z * a.z + a.w * a.w +
               bq.x * bq.x + bq.y * bq.y + bq.z * bq.z + bq.w * bq.w;
    float dt = a.x * gl[0] + a.y * gl[1] + a.z * gl[2] + a.w * gl[3] +
               bq.x * gl[4] + bq.y * gl[5] + bq.z * gl[6] + bq.w * gl[7];
    ss = waveSum(ss);
    dt = waveSum(dt);
    if (lane == 0) {
      float nv = 1.f / fmaxf(sqrtf(ss), 1e-12f);
      ninv[b * NN + n] = nv;
      s_im[b * NN + n] = dt * nv;
    }
  }
}

// ---------------- prep per caption: inverse norms -------------------------
__global__ __launch_bounds__(256) void k_prep_cap(const float* __restrict__ cap,
                                                  float* __restrict__ cinv) {
  int j = blockIdx.x, t = threadIdx.x, w = t >> 6, lane = t & 63;
  for (int m = w; m < MQ; m += 4) {
    const float* row = cap + ((size_t)j * MQ + m) * CC + lane * 8;
    float4 a = *(const float4*)row;
    float4 bq = *(const float4*)(row + 4);
    float ss = a.x * a.x + a.y * a.y + a.z * a.z + a.w * a.w +
               bq.x * bq.x + bq.y * bq.y + bq.z * bq.z + bq.w * bq.w;
    ss = waveSum(ss);
    if (lane == 0) cinv[j * MQ + m] = 1.f / fmaxf(sqrtf(ss), 1e-12f);
  }
}

// ---------------- per-token LN + MLP (j-independent hoist) ----------------
// y[token][k] for all 48*196 tokens, k<39; row stride 40.
__global__ __launch_bounds__(256) void k_mlp(const float* __restrict__ img,
                                             const float* __restrict__ ln_g,
                                             const float* __restrict__ ln_b,
                                             const float* __restrict__ w1,
                                             const float* __restrict__ b1,
                                             const float* __restrict__ w2,
                                             const float* __restrict__ b2,
                                             float* __restrict__ y) {
  __shared__ float X[32 * 513];
  __shared__ float H[32 * 105];
  __shared__ float muL[32], rsL[32];
  int t = threadIdx.x;
  int g0 = blockIdx.x * 32;
  for (int p = t; p < 32 * CC; p += 256) {
    int tok = p >> 9, cc = p & 511;
    int gi = g0 + tok;
    int b = gi / NN, n = gi - b * NN;
    X[tok * 513 + cc] = img[((size_t)b * 197 + 1 + n) * CC + cc];
  }
  __syncthreads();
  if (t < 32) {
    float sm = 0.f, ss = 0.f;
    for (int c = 0; c < CC; ++c) {
      float v = X[t * 513 + c];
      sm += v; ss += v * v;
    }
    float mu = sm * (1.f / CC);
    float var = ss * (1.f / CC) - mu * mu;
    muL[t] = mu;
    rsL[t] = rsqrtf(var + 1e-5f);
  }
  __syncthreads();
  for (int p = t; p < 32 * CC; p += 256) {
    int tok = p >> 9, cc = p & 511;
    X[tok * 513 + cc] = (X[tok * 513 + cc] - muL[tok]) * rsL[tok] * ln_g[cc] + ln_b[cc];
  }
  __syncthreads();
  {
    int tok = t & 31, hg = t >> 5;
    float acc[13];
#pragma unroll
    for (int i = 0; i < 13; ++i) {
      int h = hg * 13 + i;
      acc[i] = (h < HID) ? b1[h] : 0.f;
    }
    for (int c = 0; c < CC; ++c) {
      float xv = X[tok * 513 + c];
      const float* wr = w1 + (size_t)c * HID + hg * 13;
#pragma unroll
      for (int i = 0; i < 13; ++i) {
        int h = hg * 13 + i;
        if (h < HID) acc[i] = fmaf(xv, wr[i], acc[i]);
      }
    }
#pragma unroll
    for (int i = 0; i < 13; ++i) {
      int h = hg * 13 + i;
      if (h < HID) {
        float v = acc[i];
        H[tok * 105 + h] = 0.5f * v * (1.f + erff(v * 0.70710678118654752f));
      }
    }
  }
  __syncthreads();
  {
    int tok = t & 31, kg = t >> 5;
    float acc[5];
#pragma unroll
    for (int i = 0; i < 5; ++i) {
      int k = kg * 5 + i;
      acc[i] = (k < KEEPN) ? b2[k] : 0.f;
    }
    for (int h = 0; h < HID; ++h) {
      float hv = H[tok * 105 + h];
      const float* wr = w2 + (size_t)h * KEEPN + kg * 5;
#pragma unroll
      for (int i = 0; i < 5; ++i) {
        int k = kg * 5 + i;
        if (k < KEEPN) acc[i] = fmaf(hv, wr[i], acc[i]);
      }
    }
#pragma unroll
    for (int i = 0; i < 5; ++i) {
      int k = kg * 5 + i;
      if (k < KEEPN) y[(size_t)(g0 + tok) * 40 + k] = acc[i];
    }
  }
}

// ---------------- main per-(caption j, image b) kernel --------------------
__global__ __launch_bounds__(256) void k_main(const float* __restrict__ img,
                                              const float* __restrict__ cap,
                                              const float* __restrict__ cinvG,
                                              const float* __restrict__ ninvG,
                                              const float* __restrict__ s_imG,
                                              const float* __restrict__ yG,
                                              const float* __restrict__ scaleG,
                                              float* __restrict__ out) {
  int blk = blockIdx.x;
  int b = blk / B_T, j = blk - b * B_T;
  int t = threadIdx.x, w = t >> 6, lane = t & 63;

  __shared__ float scoreL[NN];
  __shared__ int keepI[NKEEP];
  __shared__ int nonI[NKEEP];
  __shared__ float nonSc[NKEEP];
  __shared__ float nonW[NKEEP];
  __shared__ float cinvL[MQ];
  __shared__ float yL[NKEEP * 40];
  __shared__ float extraL[CC];
  __shared__ float c2t[MQ * 42];
  __shared__ float red[256], red2[256];
  __shared__ float rowM[MQ], colM[TOKS];
  __shared__ float sc0, sc1, sc2;

  if (t < MQ) cinvL[t] = cinvG[j * MQ + t];
  __syncthreads();

  const float* capj = cap + (size_t)j * MQ * CC;

  // ---- phase 1: c2i (32x512 dots per token) -> score[n] ----
  if (t < NN) {
    const float* spn = img + ((size_t)b * 197 + 1 + t) * CC;
    float acc[MQ];
#pragma unroll
    for (int m = 0; m < MQ; ++m) acc[m] = 0.f;
    for (int c0 = 0; c0 < CC; c0 += 8) {
      float4 a0 = *(const float4*)(spn + c0);
      float4 a1 = *(const float4*)(spn + c0 + 4);
#pragma unroll
      for (int m = 0; m < MQ; ++m) {
        const float* cr = capj + m * CC + c0;  // wave-uniform -> scalar loads
        float s = acc[m];
        s = fmaf(cr[0], a0.x, s); s = fmaf(cr[1], a0.y, s);
        s = fmaf(cr[2], a0.z, s); s = fmaf(cr[3], a0.w, s);
        s = fmaf(cr[4], a1.x, s); s = fmaf(cr[5], a1.y, s);
        s = fmaf(cr[6], a1.z, s); s = fmaf(cr[7], a1.w, s);
        acc[m] = s;
      }
    }
    float attn = -INFINITY;
#pragma unroll
    for (int m = 0; m < MQ; ++m) attn = fmaxf(attn, acc[m] * cinvL[m]);
    scoreL[t] = s_imG[b * NN + t] + attn * ninvG[b * NN + t];
  }
  __syncthreads();

  // ---- phase 2: exact stable-descending rank -> keep/non partition ----
  if (t < NN) {
    float ms = scoreL[t];
    int rank = 0;
    for (int q = 0; q < NN; ++q) {
      float sq = scoreL[q];
      rank += (sq > ms) || (sq == ms && q < t);
    }
    if (rank < NKEEP) keepI[rank] = t;
    else { nonI[rank - NKEEP] = t; nonSc[rank - NKEEP] = ms; }
  }
  __syncthreads();

  // ---- stage y for keep tokens; non-softmax max/sum ----
  float scaleV = scaleG[0];
  for (int p = t; p < NKEEP * 40; p += 256) {
    int i = p / 40, k = p - i * 40;
    yL[p] = (k < KEEPN) ? yG[(size_t)(b * NN + keepI[i]) * 40 + k] : 0.f;
  }
  if (t < 64) {
    float v0 = nonSc[t];
    float v1 = (t + 64 < NKEEP) ? nonSc[t + 64] : -INFINITY;
    float mx = waveMax(fmaxf(v0, v1));
    float e = expf(v0 - mx) + ((t + 64 < NKEEP) ? expf(v1 - mx) : 0.f);
    float s = waveSum(e);
    if (t == 0) { sc0 = mx; sc1 = s; }
  }
  __syncthreads();
  if (t < NKEEP) nonW[t] = expf(nonSc[t] - sc0) / sc1;
  if (t >= 128 && t < 128 + KEEPN) {
    int k = t - 128;
    float mx = -INFINITY;
    for (int i = 0; i < NKEEP; ++i) mx = fmaxf(mx, yL[i * 40 + k] * scaleV);
    float s = 0.f;
    for (int i = 0; i < NKEEP; ++i) {
      float e = expf(yL[i * 40 + k] * scaleV - mx);
      yL[i * 40 + k] = e;
      s += e;
    }
    float rs = 1.f / s;
    for (int i = 0; i < NKEEP; ++i) yL[i * 40 + k] *= rs;
  }
  __syncthreads();

  // ---- phase 3a: extra token (non-set weighted sum) + cls norm ----
  {
    int c0 = t, c1 = t + 256;
    float e0 = 0.f, e1 = 0.f;
    for (int i = 0; i < NKEEP; ++i) {
      int r = nonI[i];
      float wv = nonW[i];
      const float* row = img + ((size_t)b * 197 + 1 + r) * CC;
      e0 = fmaf(wv, row[c0], e0);
      e1 = fmaf(wv, row[c1], e1);
    }
    float cl0 = img[(size_t)b * 197 * CC + c0];
    float cl1 = img[(size_t)b * 197 * CC + c1];
    red[t] = e0 * e0 + e1 * e1;
    red2[t] = cl0 * cl0 + cl1 * cl1;
    __syncthreads();
    for (int s = 128; s > 0; s >>= 1) {
      if (t < s) { red[t] += red[t + s]; red2[t] += red2[t + s]; }
      __syncthreads();
    }
    if (t == 0) {
      red[0] = 1.f / fmaxf(sqrtf(red[0]), 1e-12f);
      sc2 = 1.f / fmaxf(sqrtf(red2[0]), 1e-12f);
    }
    __syncthreads();
    float rnE = red[0];
    extraL[c0] = e0 * rnE;
    extraL[c1] = e1 * rnE;
  }
  __syncthreads();

  // ---- phase 4: per-wave aggr tokens (k = w+4q), normalize, c2t dots ----
  {
    float acc[10][8];
#pragma unroll
    for (int q = 0; q < 10; ++q)
#pragma unroll
      for (int e = 0; e < 8; ++e) acc[q][e] = 0.f;
    for (int i = 0; i < NKEEP; ++i) {
      int r = keepI[i];
      const float* row = img + ((size_t)b * 197 + 1 + r) * CC + lane * 8;
      float4 s0 = *(const float4*)row;
      float4 s1 = *(const float4*)(row + 4);
      float sp8[8] = {s0.x, s0.y, s0.z, s0.w, s1.x, s1.y, s1.z, s1.w};
#pragma unroll
      for (int q = 0; q < 10; ++q) {
        int k = w + 4 * q;
        if (k < KEEPN) {
          float wv = yL[i * 40 + k];
#pragma unroll
          for (int e = 0; e < 8; ++e) acc[q][e] = fmaf(wv, sp8[e], acc[q][e]);
        }
      }
    }
#pragma unroll
    for (int q = 0; q < 10; ++q) {
      int k = w + 4 * q;
      if (k < KEEPN) {
        float ss = 0.f;
#pragma unroll
        for (int e = 0; e < 8; ++e) ss += acc[q][e] * acc[q][e];
        ss = waveSum(ss);
        float rn = 1.f / fmaxf(sqrtf(ss), 1e-12f);
#pragma unroll
        for (int e = 0; e < 8; ++e) acc[q][e] *= rn;
      }
    }
    for (int m = 0; m < MQ; ++m) {
      const float* cr = capj + m * CC + lane * 8;
      float4 c0 = *(const float4*)cr;
      float4 c1 = *(const float4*)(cr + 4);
      float cp8[8] = {c0.x, c0.y, c0.z, c0.w, c1.x, c1.y, c1.z, c1.w};
#pragma unroll
      for (int q = 0; q < 10; ++q) {
        int k = w + 4 * q;
        if (k < KEEPN) {
          float p = 0.f;
#pragma unroll
          for (int e = 0; e < 8; ++e) p = fmaf(acc[q][e], cp8[e], p);
          p = waveSum(p);
          if (lane == 0) c2t[m * 42 + 1 + k] = p * cinvL[m];
        }
      }
    }
  }

  // ---- phase 5: cls + extra c2t columns (wave w -> m = 8w..8w+7) ----
  {
    const float* clsrow = img + (size_t)b * 197 * CC + lane * 8;
    float4 a0 = *(const float4*)clsrow;
    float4 a1 = *(const float4*)(clsrow + 4);
    float cls8[8] = {a0.x, a0.y, a0.z, a0.w, a1.x, a1.y, a1.z, a1.w};
    float ex8[8];
#pragma unroll
    for (int e = 0; e < 8; ++e) ex8[e] = extraL[lane * 8 + e];
    float rnC = sc2;
    for (int mi = 0; mi < 8; ++mi) {
      int m = w * 8 + mi;
      const float* cr = capj + m * CC + lane * 8;
      float4 q0 = *(const float4*)cr;
      float4 q1 = *(const float4*)(cr + 4);
      float cp8[8] = {q0.x, q0.y, q0.z, q0.w, q1.x, q1.y, q1.z, q1.w};
      float pc = 0.f, pe = 0.f;
#pragma unroll
      for (int e = 0; e < 8; ++e) {
        pc = fmaf(cls8[e], cp8[e], pc);
        pe = fmaf(ex8[e], cp8[e], pe);
      }
      pc = waveSum(pc);
      pe = waveSum(pe);
      if (lane == 0) {
        c2t[m * 42 + 0] = pc * cinvL[m] * rnC;
        c2t[m * 42 + 40] = pe * cinvL[m];
      }
    }
  }
  __syncthreads();

  // ---- phase 6: leaky + row/col means ----
  if (t < MQ) {
    float mx = -INFINITY;
    for (int tt = 0; tt < TOKS; ++tt) mx = fmaxf(mx, c2t[t * 42 + tt]);
    rowM[t] = (mx >= 0.f) ? mx : 0.1f * mx;
  } else if (t >= 64 && t < 64 + TOKS) {
    int tt = t - 64;
    float mx = -INFINITY;
    for (int m = 0; m < MQ; ++m) mx = fmaxf(mx, c2t[m * 42 + tt]);
    colM[tt] = (mx >= 0.f) ? mx : 0.1f * mx;
  }
  __syncthreads();
  if (t == 0) {
    float r = 0.f, c = 0.f;
    for (int m = 0; m < MQ; ++m) r += rowM[m];
    for (int tt = 0; tt < TOKS; ++tt) c += colM[tt];
    out[b * B_T + j] = r * (1.f / MQ) + c * (1.f / TOKS);
  }
}

extern "C" void kernel_launch(void* const* d_in, const int* in_sizes, int n_in,
                              void* d_out, int out_size, void* d_ws, size_t ws_size,
                              hipStream_t stream) {
  const float* img = (const float*)d_in[0];
  const float* cap = (const float*)d_in[1];
  // d_in[2] cap_lens unused (all == M in this problem)
  const float* ln_g = (const float*)d_in[3];
  const float* ln_b = (const float*)d_in[4];
  const float* w1 = (const float*)d_in[5];
  const float* b1 = (const float*)d_in[6];
  const float* w2 = (const float*)d_in[7];
  const float* b2 = (const float*)d_in[8];
  const float* scale = (const float*)d_in[9];
  float* ws = (float*)d_ws;
  float* cinv = ws;                          // 48*32
  float* ninv = ws + 1536;                   // 48*196
  float* s_im = ws + 1536 + 9408;            // 48*196
  float* y    = ws + 1536 + 9408 + 9408;     // 9408*40
  float* out = (float*)d_out;

  k_prep_img<<<B_V, 256, 0, stream>>>(img, ninv, s_im);
  k_prep_cap<<<B_T, 256, 0, stream>>>(cap, cinv);
  k_mlp<<<294, 256, 0, stream>>>(img, ln_g, ln_b, w1, b1, w2, b2, y);
  k_main<<<B_V * B_T, 256, 0, stream>>>(img, cap, cinv, ninv, s_im, y, scale, out);
}

// Round 2
// 1425.751 us; speedup vs baseline: 1.1207x; 1.1207x over previous
//
#include <hip/hip_runtime.h>
#include <math.h>

#define B_V 48
#define B_T 48
#define MQ 32
#define NN 196
#define CC 512
#define HID 102
#define KEEPN 39
#define NKEEP 98
#define TOKS 41

__device__ __forceinline__ float waveSum(float v) {
#pragma unroll
  for (int off = 32; off > 0; off >>= 1) v += __shfl_xor(v, off, 64);
  return v;
}
__device__ __forceinline__ float waveMax(float v) {
#pragma unroll
  for (int off = 32; off > 0; off >>= 1) v = fmaxf(v, __shfl_xor(v, off, 64));
  return v;
}

// ---------------- prep per image: glo, s_im, spatial inverse norms --------
__global__ __launch_bounds__(256) void k_prep_img(const float* __restrict__ img,
                                                  float* __restrict__ ninv,
                                                  float* __restrict__ s_im) {
  int b = blockIdx.x, t = threadIdx.x;
  __shared__ float glo[CC];
  __shared__ float red[256];
  __shared__ float rgS;
  const float* sp = img + ((size_t)b * 197 + 1) * CC;
  float v0 = 0.f, v1 = 0.f;
  for (int n = 0; n < NN; ++n) {
    v0 += sp[(size_t)n * CC + t];
    v1 += sp[(size_t)n * CC + t + 256];
  }
  v0 *= (1.f / NN); v1 *= (1.f / NN);
  glo[t] = v0; glo[t + 256] = v1;
  red[t] = v0 * v0 + v1 * v1;
  __syncthreads();
  for (int s = 128; s > 0; s >>= 1) {
    if (t < s) red[t] += red[t + s];
    __syncthreads();
  }
  if (t == 0) rgS = 1.f / fmaxf(sqrtf(red[0]), 1e-12f);
  __syncthreads();
  float rg = rgS;
  glo[t] *= rg; glo[t + 256] *= rg;
  __syncthreads();
  int w = t >> 6, lane = t & 63;
  for (int n = w; n < NN; n += 4) {
    const float* row = sp + (size_t)n * CC + lane * 8;
    float4 a = *(const float4*)row;
    float4 bq = *(const float4*)(row + 4);
    const float* gl = glo + lane * 8;
    float ss = a.x * a.x + a.y * a.y + a.z * a.z + a.w * a.w +
               bq.x * bq.x + bq.y * bq.y + bq.z * bq.z + bq.w * bq.w;
    float dt = a.x * gl[0] + a.y * gl[1] + a.z * gl[2] + a.w * gl[3] +
               bq.x * gl[4] + bq.y * gl[5] + bq.z * gl[6] + bq.w * gl[7];
    ss = waveSum(ss);
    dt = waveSum(dt);
    if (lane == 0) {
      float nv = 1.f / fmaxf(sqrtf(ss), 1e-12f);
      ninv[b * NN + n] = nv;
      s_im[b * NN + n] = dt * nv;
    }
  }
}

// ---------------- prep per caption: inverse norms -------------------------
__global__ __launch_bounds__(256) void k_prep_cap(const float* __restrict__ cap,
                                                  float* __restrict__ cinv) {
  int j = blockIdx.x, t = threadIdx.x, w = t >> 6, lane = t & 63;
  for (int m = w; m < MQ; m += 4) {
    const float* row = cap + ((size_t)j * MQ + m) * CC + lane * 8;
    float4 a = *(const float4*)row;
    float4 bq = *(const float4*)(row + 4);
    float ss = a.x * a.x + a.y * a.y + a.z * a.z + a.w * a.w +
               bq.x * bq.x + bq.y * bq.y + bq.z * bq.z + bq.w * bq.w;
    ss = waveSum(ss);
    if (lane == 0) cinv[j * MQ + m] = 1.f / fmaxf(sqrtf(ss), 1e-12f);
  }
}

// ---------------- per-token LN + MLP (j-independent hoist) ----------------
__global__ __launch_bounds__(256) void k_mlp(const float* __restrict__ img,
                                             const float* __restrict__ ln_g,
                                             const float* __restrict__ ln_b,
                                             const float* __restrict__ w1,
                                             const float* __restrict__ b1,
                                             const float* __restrict__ w2,
                                             const float* __restrict__ b2,
                                             float* __restrict__ y) {
  __shared__ float X[32 * 513];
  __shared__ float H[32 * 105];
  __shared__ float muL[32], rsL[32];
  int t = threadIdx.x;
  int g0 = blockIdx.x * 32;
  for (int p = t; p < 32 * CC; p += 256) {
    int tok = p >> 9, cc = p & 511;
    int gi = g0 + tok;
    int b = gi / NN, n = gi - b * NN;
    X[tok * 513 + cc] = img[((size_t)b * 197 + 1 + n) * CC + cc];
  }
  __syncthreads();
  if (t < 32) {
    float sm = 0.f, ss = 0.f;
    for (int c = 0; c < CC; ++c) {
      float v = X[t * 513 + c];
      sm += v; ss += v * v;
    }
    float mu = sm * (1.f / CC);
    float var = ss * (1.f / CC) - mu * mu;
    muL[t] = mu;
    rsL[t] = rsqrtf(var + 1e-5f);
  }
  __syncthreads();
  for (int p = t; p < 32 * CC; p += 256) {
    int tok = p >> 9, cc = p & 511;
    X[tok * 513 + cc] = (X[tok * 513 + cc] - muL[tok]) * rsL[tok] * ln_g[cc] + ln_b[cc];
  }
  __syncthreads();
  {
    int tok = t & 31, hg = t >> 5;
    float acc[13];
#pragma unroll
    for (int i = 0; i < 13; ++i) {
      int h = hg * 13 + i;
      acc[i] = (h < HID) ? b1[h] : 0.f;
    }
    for (int c = 0; c < CC; ++c) {
      float xv = X[tok * 513 + c];
      const float* wr = w1 + (size_t)c * HID + hg * 13;
#pragma unroll
      for (int i = 0; i < 13; ++i) {
        int h = hg * 13 + i;
        if (h < HID) acc[i] = fmaf(xv, wr[i], acc[i]);
      }
    }
#pragma unroll
    for (int i = 0; i < 13; ++i) {
      int h = hg * 13 + i;
      if (h < HID) {
        float v = acc[i];
        H[tok * 105 + h] = 0.5f * v * (1.f + erff(v * 0.70710678118654752f));
      }
    }
  }
  __syncthreads();
  {
    int tok = t & 31, kg = t >> 5;
    float acc[5];
#pragma unroll
    for (int i = 0; i < 5; ++i) {
      int k = kg * 5 + i;
      acc[i] = (k < KEEPN) ? b2[k] : 0.f;
    }
    for (int h = 0; h < HID; ++h) {
      float hv = H[tok * 105 + h];
      const float* wr = w2 + (size_t)h * KEEPN + kg * 5;
#pragma unroll
      for (int i = 0; i < 5; ++i) {
        int k = kg * 5 + i;
        if (k < KEEPN) acc[i] = fmaf(hv, wr[i], acc[i]);
      }
    }
#pragma unroll
    for (int i = 0; i < 5; ++i) {
      int k = kg * 5 + i;
      if (k < KEEPN) y[(size_t)(g0 + tok) * 40 + k] = acc[i];
    }
  }
}

// ---------------- score kernel: c2i + max over m, cap operand via s_load --
typedef __attribute__((ext_vector_type(8))) float f32x8;

#define SL8(dst, off_lit) \
  asm volatile("s_load_dwordx8 %0, %1, " off_lit : "=s"(dst) : "s"(bp))

#define SWAIT8() \
  asm volatile("s_waitcnt lgkmcnt(0)" \
               : "+s"(s0), "+s"(s1), "+s"(s2), "+s"(s3), \
                 "+s"(s4), "+s"(s5), "+s"(s6), "+s"(s7))

#define DOT8(S, I) do { float t_ = acc[I]; \
  t_ = fmaf(S[0], a[0], t_); t_ = fmaf(S[1], a[1], t_); \
  t_ = fmaf(S[2], a[2], t_); t_ = fmaf(S[3], a[3], t_); \
  t_ = fmaf(S[4], a[4], t_); t_ = fmaf(S[5], a[5], t_); \
  t_ = fmaf(S[6], a[6], t_); t_ = fmaf(S[7], a[7], t_); \
  acc[I] = t_; } while (0)

__global__ __launch_bounds__(256, 6) void k_score(const float* __restrict__ img,
                                                  const float* __restrict__ cap,
                                                  const float* __restrict__ cinvG,
                                                  const float* __restrict__ ninvG,
                                                  const float* __restrict__ s_imG,
                                                  float* __restrict__ scoreG) {
  int blk = blockIdx.x;
  int b = blk / B_T, j = blk - b * B_T;
  int t = threadIdx.x;
  if (t >= NN) return;

  const float* capj = cap + (size_t)j * MQ * CC;
  const float* spn = img + ((size_t)b * 197 + 1 + t) * CC;

  float acc[MQ];
#pragma unroll
  for (int m = 0; m < MQ; ++m) acc[m] = 0.f;

  for (int k0 = 0; k0 < CC; k0 += 8) {
    float4 a0 = *(const float4*)(spn + k0);
    float4 a1 = *(const float4*)(spn + k0 + 4);
    float a[8] = {a0.x, a0.y, a0.z, a0.w, a1.x, a1.y, a1.z, a1.w};
    const float* bp = capj + k0;
    f32x8 s0, s1, s2, s3, s4, s5, s6, s7;
    // m rows 0..7
    SL8(s0, "0x0");    SL8(s1, "0x800");  SL8(s2, "0x1000"); SL8(s3, "0x1800");
    SL8(s4, "0x2000"); SL8(s5, "0x2800"); SL8(s6, "0x3000"); SL8(s7, "0x3800");
    SWAIT8();
    DOT8(s0, 0); DOT8(s1, 1); DOT8(s2, 2); DOT8(s3, 3);
    DOT8(s4, 4); DOT8(s5, 5); DOT8(s6, 6); DOT8(s7, 7);
    // m rows 8..15
    SL8(s0, "0x4000"); SL8(s1, "0x4800"); SL8(s2, "0x5000"); SL8(s3, "0x5800");
    SL8(s4, "0x6000"); SL8(s5, "0x6800"); SL8(s6, "0x7000"); SL8(s7, "0x7800");
    SWAIT8();
    DOT8(s0, 8); DOT8(s1, 9); DOT8(s2, 10); DOT8(s3, 11);
    DOT8(s4, 12); DOT8(s5, 13); DOT8(s6, 14); DOT8(s7, 15);
    // m rows 16..23
    SL8(s0, "0x8000"); SL8(s1, "0x8800"); SL8(s2, "0x9000"); SL8(s3, "0x9800");
    SL8(s4, "0xA000"); SL8(s5, "0xA800"); SL8(s6, "0xB000"); SL8(s7, "0xB800");
    SWAIT8();
    DOT8(s0, 16); DOT8(s1, 17); DOT8(s2, 18); DOT8(s3, 19);
    DOT8(s4, 20); DOT8(s5, 21); DOT8(s6, 22); DOT8(s7, 23);
    // m rows 24..31
    SL8(s0, "0xC000"); SL8(s1, "0xC800"); SL8(s2, "0xD000"); SL8(s3, "0xD800");
    SL8(s4, "0xE000"); SL8(s5, "0xE800"); SL8(s6, "0xF000"); SL8(s7, "0xF800");
    SWAIT8();
    DOT8(s0, 24); DOT8(s1, 25); DOT8(s2, 26); DOT8(s3, 27);
    DOT8(s4, 28); DOT8(s5, 29); DOT8(s6, 30); DOT8(s7, 31);
  }

  float attn = -INFINITY;
#pragma unroll
  for (int m = 0; m < MQ; ++m) attn = fmaxf(attn, acc[m] * cinvG[j * MQ + m]);
  scoreG[(size_t)blk * NN + t] = s_imG[b * NN + t] + attn * ninvG[b * NN + t];
}

// ---------------- main per-(caption j, image b) kernel (post-score) ------
__global__ __launch_bounds__(256, 4) void k_main2(const float* __restrict__ img,
                                                  const float* __restrict__ cap,
                                                  const float* __restrict__ cinvG,
                                                  const float* __restrict__ scoreG,
                                                  const float* __restrict__ yG,
                                                  const float* __restrict__ scaleG,
                                                  float* __restrict__ out) {
  int blk = blockIdx.x;
  int b = blk / B_T, j = blk - b * B_T;
  int t = threadIdx.x, w = t >> 6, lane = t & 63;

  __shared__ float scoreL[NN];
  __shared__ int keepI[NKEEP];
  __shared__ int nonI[NKEEP];
  __shared__ float nonSc[NKEEP];
  __shared__ float nonW[NKEEP];
  __shared__ float cinvL[MQ];
  __shared__ float yL[NKEEP * 40];
  __shared__ float extraL[CC];
  __shared__ float c2t[MQ * 42];
  __shared__ float red[256], red2[256];
  __shared__ float rowM[MQ], colM[TOKS];
  __shared__ float sc0, sc1, sc2;

  if (t < MQ) cinvL[t] = cinvG[j * MQ + t];
  if (t < NN) scoreL[t] = scoreG[(size_t)blk * NN + t];
  __syncthreads();

  const float* capj = cap + (size_t)j * MQ * CC;

  // ---- exact stable-descending rank -> keep/non partition ----
  if (t < NN) {
    float ms = scoreL[t];
    int rank = 0;
    for (int q = 0; q < NN; ++q) {
      float sq = scoreL[q];
      rank += (sq > ms) || (sq == ms && q < t);
    }
    if (rank < NKEEP) keepI[rank] = t;
    else { nonI[rank - NKEEP] = t; nonSc[rank - NKEEP] = ms; }
  }
  __syncthreads();

  // ---- stage y for keep tokens; non-softmax max/sum ----
  float scaleV = scaleG[0];
  for (int p = t; p < NKEEP * 40; p += 256) {
    int i = p / 40, k = p - i * 40;
    yL[p] = (k < KEEPN) ? yG[(size_t)(b * NN + keepI[i]) * 40 + k] : 0.f;
  }
  if (t < 64) {
    float v0 = nonSc[t];
    float v1 = (t + 64 < NKEEP) ? nonSc[t + 64] : -INFINITY;
    float mx = waveMax(fmaxf(v0, v1));
    float e = expf(v0 - mx) + ((t + 64 < NKEEP) ? expf(v1 - mx) : 0.f);
    float s = waveSum(e);
    if (t == 0) { sc0 = mx; sc1 = s; }
  }
  __syncthreads();
  if (t < NKEEP) nonW[t] = expf(nonSc[t] - sc0) / sc1;
  if (t >= 128 && t < 128 + KEEPN) {
    int k = t - 128;
    float mx = -INFINITY;
    for (int i = 0; i < NKEEP; ++i) mx = fmaxf(mx, yL[i * 40 + k] * scaleV);
    float s = 0.f;
    for (int i = 0; i < NKEEP; ++i) {
      float e = expf(yL[i * 40 + k] * scaleV - mx);
      yL[i * 40 + k] = e;
      s += e;
    }
    float rs = 1.f / s;
    for (int i = 0; i < NKEEP; ++i) yL[i * 40 + k] *= rs;
  }
  __syncthreads();

  // ---- extra token (non-set weighted sum) + cls norm ----
  {
    int c0 = t, c1 = t + 256;
    float e0 = 0.f, e1 = 0.f;
    for (int i = 0; i < NKEEP; ++i) {
      int r = nonI[i];
      float wv = nonW[i];
      const float* row = img + ((size_t)b * 197 + 1 + r) * CC;
      e0 = fmaf(wv, row[c0], e0);
      e1 = fmaf(wv, row[c1], e1);
    }
    float cl0 = img[(size_t)b * 197 * CC + c0];
    float cl1 = img[(size_t)b * 197 * CC + c1];
    red[t] = e0 * e0 + e1 * e1;
    red2[t] = cl0 * cl0 + cl1 * cl1;
    __syncthreads();
    for (int s = 128; s > 0; s >>= 1) {
      if (t < s) { red[t] += red[t + s]; red2[t] += red2[t + s]; }
      __syncthreads();
    }
    if (t == 0) {
      red[0] = 1.f / fmaxf(sqrtf(red[0]), 1e-12f);
      sc2 = 1.f / fmaxf(sqrtf(red2[0]), 1e-12f);
    }
    __syncthreads();
    float rnE = red[0];
    extraL[c0] = e0 * rnE;
    extraL[c1] = e1 * rnE;
  }
  __syncthreads();

  // ---- per-wave aggr tokens (k = w+4q), normalize, c2t dots ----
  {
    float acc[10][8];
#pragma unroll
    for (int q = 0; q < 10; ++q)
#pragma unroll
      for (int e = 0; e < 8; ++e) acc[q][e] = 0.f;
    for (int i = 0; i < NKEEP; ++i) {
      int r = keepI[i];
      const float* row = img + ((size_t)b * 197 + 1 + r) * CC + lane * 8;
      float4 s0 = *(const float4*)row;
      float4 s1 = *(const float4*)(row + 4);
      float sp8[8] = {s0.x, s0.y, s0.z, s0.w, s1.x, s1.y, s1.z, s1.w};
#pragma unroll
      for (int q = 0; q < 10; ++q) {
        int k = w + 4 * q;
        if (k < KEEPN) {
          float wv = yL[i * 40 + k];
#pragma unroll
          for (int e = 0; e < 8; ++e) acc[q][e] = fmaf(wv, sp8[e], acc[q][e]);
        }
      }
    }
#pragma unroll
    for (int q = 0; q < 10; ++q) {
      int k = w + 4 * q;
      if (k < KEEPN) {
        float ss = 0.f;
#pragma unroll
        for (int e = 0; e < 8; ++e) ss += acc[q][e] * acc[q][e];
        ss = waveSum(ss);
        float rn = 1.f / fmaxf(sqrtf(ss), 1e-12f);
#pragma unroll
        for (int e = 0; e < 8; ++e) acc[q][e] *= rn;
      }
    }
    for (int m = 0; m < MQ; ++m) {
      const float* cr = capj + m * CC + lane * 8;
      float4 c0 = *(const float4*)cr;
      float4 c1 = *(const float4*)(cr + 4);
      float cp8[8] = {c0.x, c0.y, c0.z, c0.w, c1.x, c1.y, c1.z, c1.w};
#pragma unroll
      for (int q = 0; q < 10; ++q) {
        int k = w + 4 * q;
        if (k < KEEPN) {
          float p = 0.f;
#pragma unroll
          for (int e = 0; e < 8; ++e) p = fmaf(acc[q][e], cp8[e], p);
          p = waveSum(p);
          if (lane == 0) c2t[m * 42 + 1 + k] = p * cinvL[m];
        }
      }
    }
  }

  // ---- cls + extra c2t columns (wave w -> m = 8w..8w+7) ----
  {
    const float* clsrow = img + (size_t)b * 197 * CC + lane * 8;
    float4 a0 = *(const float4*)clsrow;
    float4 a1 = *(const float4*)(clsrow + 4);
    float cls8[8] = {a0.x, a0.y, a0.z, a0.w, a1.x, a1.y, a1.z, a1.w};
    float ex8[8];
#pragma unroll
    for (int e = 0; e < 8; ++e) ex8[e] = extraL[lane * 8 + e];
    float rnC = sc2;
    for (int mi = 0; mi < 8; ++mi) {
      int m = w * 8 + mi;
      const float* cr = capj + m * CC + lane * 8;
      float4 q0 = *(const float4*)cr;
      float4 q1 = *(const float4*)(cr + 4);
      float cp8[8] = {q0.x, q0.y, q0.z, q0.w, q1.x, q1.y, q1.z, q1.w};
      float pc = 0.f, pe = 0.f;
#pragma unroll
      for (int e = 0; e < 8; ++e) {
        pc = fmaf(cls8[e], cp8[e], pc);
        pe = fmaf(ex8[e], cp8[e], pe);
      }
      pc = waveSum(pc);
      pe = waveSum(pe);
      if (lane == 0) {
        c2t[m * 42 + 0] = pc * cinvL[m] * rnC;
        c2t[m * 42 + 40] = pe * cinvL[m];
      }
    }
  }
  __syncthreads();

  // ---- leaky + row/col means ----
  if (t < MQ) {
    float mx = -INFINITY;
    for (int tt = 0; tt < TOKS; ++tt) mx = fmaxf(mx, c2t[t * 42 + tt]);
    rowM[t] = (mx >= 0.f) ? mx : 0.1f * mx;
  } else if (t >= 64 && t < 64 + TOKS) {
    int tt = t - 64;
    float mx = -INFINITY;
    for (int m = 0; m < MQ; ++m) mx = fmaxf(mx, c2t[m * 42 + tt]);
    colM[tt] = (mx >= 0.f) ? mx : 0.1f * mx;
  }
  __syncthreads();
  if (t == 0) {
    float r = 0.f, c = 0.f;
    for (int m = 0; m < MQ; ++m) r += rowM[m];
    for (int tt = 0; tt < TOKS; ++tt) c += colM[tt];
    out[b * B_T + j] = r * (1.f / MQ) + c * (1.f / TOKS);
  }
}

extern "C" void kernel_launch(void* const* d_in, const int* in_sizes, int n_in,
                              void* d_out, int out_size, void* d_ws, size_t ws_size,
                              hipStream_t stream) {
  const float* img = (const float*)d_in[0];
  const float* cap = (const float*)d_in[1];
  const float* ln_g = (const float*)d_in[3];
  const float* ln_b = (const float*)d_in[4];
  const float* w1 = (const float*)d_in[5];
  const float* b1 = (const float*)d_in[6];
  const float* w2 = (const float*)d_in[7];
  const float* b2 = (const float*)d_in[8];
  const float* scale = (const float*)d_in[9];
  float* ws = (float*)d_ws;
  float* cinv = ws;                              // 48*32      = 1536
  float* ninv = ws + 1536;                       // 48*196     = 9408
  float* s_im = ws + 1536 + 9408;                // 48*196     = 9408
  float* y    = ws + 1536 + 9408 + 9408;         // 9408*40    = 376320
  float* scoreW = ws + 1536 + 9408 + 9408 + 376320;  // 2304*196
  float* out = (float*)d_out;

  k_prep_img<<<B_V, 256, 0, stream>>>(img, ninv, s_im);
  k_prep_cap<<<B_T, 256, 0, stream>>>(cap, cinv);
  k_mlp<<<294, 256, 0, stream>>>(img, ln_g, ln_b, w1, b1, w2, b2, y);
  k_score<<<B_V * B_T, 256, 0, stream>>>(img, cap, cinv, ninv, s_im, scoreW);
  k_main2<<<B_V * B_T, 256, 0, stream>>>(img, cap, cinv, scoreW, y, scale, out);
}

// Round 4
// 939.227 us; speedup vs baseline: 1.7012x; 1.5180x over previous
//
#include <hip/hip_runtime.h>
#include <math.h>
#include <stdint.h>

#define B_V 48
#define B_T 48
#define MQ 32
#define NN 196
#define CC 512
#define HID 102
#define KEEPN 39
#define NKEEP 98
#define TOKS 41

__device__ __forceinline__ float waveSum(float v) {
#pragma unroll
  for (int off = 32; off > 0; off >>= 1) v += __shfl_xor(v, off, 64);
  return v;
}
__device__ __forceinline__ float waveMax(float v) {
#pragma unroll
  for (int off = 32; off > 0; off >>= 1) v = fmaxf(v, __shfl_xor(v, off, 64));
  return v;
}

// ---------------- prep per image: glo, s_im, spatial inverse norms --------
__global__ __launch_bounds__(256) void k_prep_img(const float* __restrict__ img,
                                                  float* __restrict__ ninv,
                                                  float* __restrict__ s_im) {
  int b = blockIdx.x, t = threadIdx.x;
  __shared__ float glo[CC];
  __shared__ float red[256];
  __shared__ float rgS;
  const float* sp = img + ((size_t)b * 197 + 1) * CC;
  float v0 = 0.f, v1 = 0.f;
  for (int n = 0; n < NN; ++n) {
    v0 += sp[(size_t)n * CC + t];
    v1 += sp[(size_t)n * CC + t + 256];
  }
  v0 *= (1.f / NN); v1 *= (1.f / NN);
  glo[t] = v0; glo[t + 256] = v1;
  red[t] = v0 * v0 + v1 * v1;
  __syncthreads();
  for (int s = 128; s > 0; s >>= 1) {
    if (t < s) red[t] += red[t + s];
    __syncthreads();
  }
  if (t == 0) rgS = 1.f / fmaxf(sqrtf(red[0]), 1e-12f);
  __syncthreads();
  float rg = rgS;
  glo[t] *= rg; glo[t + 256] *= rg;
  __syncthreads();
  int w = t >> 6, lane = t & 63;
  for (int n = w; n < NN; n += 4) {
    const float* row = sp + (size_t)n * CC + lane * 8;
    float4 a = *(const float4*)row;
    float4 bq = *(const float4*)(row + 4);
    const float* gl = glo + lane * 8;
    float ss = a.x * a.x + a.y * a.y + a.z * a.z + a.w * a.w +
               bq.x * bq.x + bq.y * bq.y + bq.z * bq.z + bq.w * bq.w;
    float dt = a.x * gl[0] + a.y * gl[1] + a.z * gl[2] + a.w * gl[3] +
               bq.x * gl[4] + bq.y * gl[5] + bq.z * gl[6] + bq.w * gl[7];
    ss = waveSum(ss);
    dt = waveSum(dt);
    if (lane == 0) {
      float nv = 1.f / fmaxf(sqrtf(ss), 1e-12f);
      ninv[b * NN + n] = nv;
      s_im[b * NN + n] = dt * nv;
    }
  }
}

// ---------------- prep per caption: inverse norms -------------------------
__global__ __launch_bounds__(256) void k_prep_cap(const float* __restrict__ cap,
                                                  float* __restrict__ cinv) {
  int j = blockIdx.x, t = threadIdx.x, w = t >> 6, lane = t & 63;
  for (int m = w; m < MQ; m += 4) {
    const float* row = cap + ((size_t)j * MQ + m) * CC + lane * 8;
    float4 a = *(const float4*)row;
    float4 bq = *(const float4*)(row + 4);
    float ss = a.x * a.x + a.y * a.y + a.z * a.z + a.w * a.w +
               bq.x * bq.x + bq.y * bq.y + bq.z * bq.z + bq.w * bq.w;
    ss = waveSum(ss);
    if (lane == 0) cinv[j * MQ + m] = 1.f / fmaxf(sqrtf(ss), 1e-12f);
  }
}

// ---------------- fold LN into w1: w1gT[j][c] = g[c]*w1[c][j]; A,B --------
__global__ __launch_bounds__(256) void k_fold(const float* __restrict__ w1,
                                              const float* __restrict__ b1,
                                              const float* __restrict__ ln_g,
                                              const float* __restrict__ ln_b,
                                              float* __restrict__ w1gT,
                                              float* __restrict__ A,
                                              float* __restrict__ Bc) {
  int j = blockIdx.x, t = threadIdx.x;
  __shared__ float r1[4], r2[4];
  float v0 = 0.f, v1 = 0.f, ba = 0.f;
  if (j < HID) {
    float wv0 = w1[(size_t)t * HID + j];
    float wv1 = w1[(size_t)(t + 256) * HID + j];
    v0 = ln_g[t] * wv0;
    v1 = ln_g[t + 256] * wv1;
    ba = ln_b[t] * wv0 + ln_b[t + 256] * wv1;
  }
  w1gT[(size_t)j * 512 + t] = v0;
  w1gT[(size_t)j * 512 + t + 256] = v1;
  float aa = waveSum(v0 + v1);
  float bb = waveSum(ba);
  int wv = t >> 6, lane = t & 63;
  if (lane == 0) { r1[wv] = aa; r2[wv] = bb; }
  __syncthreads();
  if (t == 0) {
    float sa = r1[0] + r1[1] + r1[2] + r1[3];
    float sb = r2[0] + r2[1] + r2[2] + r2[3];
    A[j] = (j < HID) ? sa : 0.f;
    Bc[j] = (j < HID) ? (sb + b1[j]) : 0.f;
  }
}

// ---------------- per-token LN stats ----------------
__global__ __launch_bounds__(256) void k_ln(const float* __restrict__ img,
                                            float* __restrict__ muG,
                                            float* __restrict__ rsG) {
  int t = threadIdx.x, wv = t >> 6, lane = t & 63;
  int tokG = blockIdx.x * 4 + wv;
  int b = tokG / NN, n = tokG - b * NN;
  const float* row = img + ((size_t)b * 197 + 1 + n) * CC + lane * 8;
  float4 a = *(const float4*)row;
  float4 bq = *(const float4*)(row + 4);
  float sm = a.x + a.y + a.z + a.w + bq.x + bq.y + bq.z + bq.w;
  float ss = a.x * a.x + a.y * a.y + a.z * a.z + a.w * a.w +
             bq.x * bq.x + bq.y * bq.y + bq.z * bq.z + bq.w * bq.w;
  sm = waveSum(sm);
  ss = waveSum(ss);
  if (lane == 0) {
    float mu = sm * (1.f / CC);
    float var = ss * (1.f / CC) - mu * mu;
    muG[tokG] = mu;
    rsG[tokG] = rsqrtf(var + 1e-5f);
  }
}

// ---------------- s_load helpers ----------------
typedef __attribute__((ext_vector_type(8))) float f32x8;

#define SL8(dst, off_lit) \
  asm volatile("s_load_dwordx8 %0, %1, " off_lit : "=s"(dst) : "s"(bp))

#define SWAIT8() \
  asm volatile("s_waitcnt lgkmcnt(0)" \
               : "+s"(s0), "+s"(s1), "+s"(s2), "+s"(s3), \
                 "+s"(s4), "+s"(s5), "+s"(s6), "+s"(s7))

#define SWAIT5() \
  asm volatile("s_waitcnt lgkmcnt(0)" \
               : "+s"(s0), "+s"(s1), "+s"(s2), "+s"(s3), "+s"(s4))

#define DOT8(S, I) do { float t_ = acc[I]; \
  t_ = fmaf(S[0], a[0], t_); t_ = fmaf(S[1], a[1], t_); \
  t_ = fmaf(S[2], a[2], t_); t_ = fmaf(S[3], a[3], t_); \
  t_ = fmaf(S[4], a[4], t_); t_ = fmaf(S[5], a[5], t_); \
  t_ = fmaf(S[6], a[6], t_); t_ = fmaf(S[7], a[7], t_); \
  acc[I] = t_; } while (0)

// ---------------- fused x@w1g (+gelu) @ w2 per 64-token tile --------------
__global__ __launch_bounds__(512, 2) void k_gemm(const float* __restrict__ img,
                                                 const float* __restrict__ w1gT,
                                                 const float* __restrict__ A,
                                                 const float* __restrict__ Bc,
                                                 const float* __restrict__ muG,
                                                 const float* __restrict__ rsG,
                                                 const float* __restrict__ w2,
                                                 const float* __restrict__ b2,
                                                 float* __restrict__ y) {
  __shared__ float hL[64 * 105];
  __shared__ float w2L[HID * 40];
  int t = threadIdx.x;
  int tok = t & 63, wv = t >> 6;
  int tokG = blockIdx.x * 64 + tok;
  int b = tokG / NN, n = tokG - b * NN;
  const float* xrow = img + ((size_t)b * 197 + 1 + n) * CC;

  for (int p = t; p < HID * 40; p += 512) {
    int j = p / 40, k = p - j * 40;
    w2L[p] = (k < KEEPN) ? w2[(size_t)j * KEEPN + k] : 0.f;
  }

  int jbase = wv * 13;  // 8 waves x 13 = 104 (rows 102,103 are zero-padded)
  // jbase is wave-uniform but threadIdx-derived -> force the s_load base
  // into the scalar domain via readfirstlane (valid: same for all 64 lanes).
  uint64_t a64 = (uint64_t)(w1gT + (size_t)jbase * 512);
  uint32_t alo = __builtin_amdgcn_readfirstlane((uint32_t)a64);
  uint32_t ahi = __builtin_amdgcn_readfirstlane((uint32_t)(a64 >> 32));
  uint64_t sbase = ((uint64_t)ahi << 32) | alo;

  float acc[13];
#pragma unroll
  for (int i = 0; i < 13; ++i) acc[i] = 0.f;

  float4 c0 = *(const float4*)(xrow);
  float4 c1 = *(const float4*)(xrow + 4);
  for (int k0 = 0; k0 < CC; k0 += 8) {
    float4 nx0, nx1;
    if (k0 + 8 < CC) {
      nx0 = *(const float4*)(xrow + k0 + 8);
      nx1 = *(const float4*)(xrow + k0 + 12);
    } else {
      nx0 = c0; nx1 = c1;
    }
    float a[8] = {c0.x, c0.y, c0.z, c0.w, c1.x, c1.y, c1.z, c1.w};
    const uint64_t bp = sbase + (uint64_t)k0 * 4;
    f32x8 s0, s1, s2, s3, s4, s5, s6, s7;
    SL8(s0, "0x0");    SL8(s1, "0x800");  SL8(s2, "0x1000"); SL8(s3, "0x1800");
    SL8(s4, "0x2000"); SL8(s5, "0x2800"); SL8(s6, "0x3000"); SL8(s7, "0x3800");
    SWAIT8();
    DOT8(s0, 0); DOT8(s1, 1); DOT8(s2, 2); DOT8(s3, 3);
    DOT8(s4, 4); DOT8(s5, 5); DOT8(s6, 6); DOT8(s7, 7);
    SL8(s0, "0x4000"); SL8(s1, "0x4800"); SL8(s2, "0x5000"); SL8(s3, "0x5800");
    SL8(s4, "0x6000");
    SWAIT5();
    DOT8(s0, 8); DOT8(s1, 9); DOT8(s2, 10); DOT8(s3, 11); DOT8(s4, 12);
    c0 = nx0; c1 = nx1;
  }

  float mu = muG[tokG], rsg = rsG[tokG];
  float nmr = -rsg * mu;
#pragma unroll
  for (int i = 0; i < 13; ++i) {
    int j = jbase + i;
    float h = fmaf(rsg, acc[i], fmaf(nmr, A[j], Bc[j]));
    hL[tok * 105 + j] = 0.5f * h * (1.f + erff(h * 0.70710678118654752f));
  }
  __syncthreads();

  // GEMM2: y[tok,k] = sum_j h[j] * w2[j,k] + b2[k]
  int kg = wv;  // 0..7, 5 k's each (40 slots >= 39)
  float acc2[5];
#pragma unroll
  for (int i = 0; i < 5; ++i) {
    int k = kg * 5 + i;
    acc2[i] = (k < KEEPN) ? b2[k] : 0.f;
  }
  for (int j = 0; j < HID; ++j) {
    float hv = hL[tok * 105 + j];
#pragma unroll
    for (int i = 0; i < 5; ++i) {
      int k = kg * 5 + i;
      if (k < KEEPN) acc2[i] = fmaf(hv, w2L[j * 40 + k], acc2[i]);
    }
  }
#pragma unroll
  for (int i = 0; i < 5; ++i) {
    int k = kg * 5 + i;
    if (k < KEEPN) y[(size_t)tokG * 40 + k] = acc2[i];
  }
}

// ---------------- score kernel: c2i + max over m, cap operand via s_load --
__global__ __launch_bounds__(256, 6) void k_score(const float* __restrict__ img,
                                                  const float* __restrict__ cap,
                                                  const float* __restrict__ cinvG,
                                                  const float* __restrict__ ninvG,
                                                  const float* __restrict__ s_imG,
                                                  float* __restrict__ scoreG) {
  int blk = blockIdx.x;
  int b = blk / B_T, j = blk - b * B_T;
  int t = threadIdx.x;
  if (t >= NN) return;

  const float* capj = cap + (size_t)j * MQ * CC;
  const float* spn = img + ((size_t)b * 197 + 1 + t) * CC;

  float acc[MQ];
#pragma unroll
  for (int m = 0; m < MQ; ++m) acc[m] = 0.f;

  for (int k0 = 0; k0 < CC; k0 += 8) {
    float4 a0 = *(const float4*)(spn + k0);
    float4 a1 = *(const float4*)(spn + k0 + 4);
    float a[8] = {a0.x, a0.y, a0.z, a0.w, a1.x, a1.y, a1.z, a1.w};
    const float* bp = capj + k0;
    f32x8 s0, s1, s2, s3, s4, s5, s6, s7;
    SL8(s0, "0x0");    SL8(s1, "0x800");  SL8(s2, "0x1000"); SL8(s3, "0x1800");
    SL8(s4, "0x2000"); SL8(s5, "0x2800"); SL8(s6, "0x3000"); SL8(s7, "0x3800");
    SWAIT8();
    DOT8(s0, 0); DOT8(s1, 1); DOT8(s2, 2); DOT8(s3, 3);
    DOT8(s4, 4); DOT8(s5, 5); DOT8(s6, 6); DOT8(s7, 7);
    SL8(s0, "0x4000"); SL8(s1, "0x4800"); SL8(s2, "0x5000"); SL8(s3, "0x5800");
    SL8(s4, "0x6000"); SL8(s5, "0x6800"); SL8(s6, "0x7000"); SL8(s7, "0x7800");
    SWAIT8();
    DOT8(s0, 8); DOT8(s1, 9); DOT8(s2, 10); DOT8(s3, 11);
    DOT8(s4, 12); DOT8(s5, 13); DOT8(s6, 14); DOT8(s7, 15);
    SL8(s0, "0x8000"); SL8(s1, "0x8800"); SL8(s2, "0x9000"); SL8(s3, "0x9800");
    SL8(s4, "0xA000"); SL8(s5, "0xA800"); SL8(s6, "0xB000"); SL8(s7, "0xB800");
    SWAIT8();
    DOT8(s0, 16); DOT8(s1, 17); DOT8(s2, 18); DOT8(s3, 19);
    DOT8(s4, 20); DOT8(s5, 21); DOT8(s6, 22); DOT8(s7, 23);
    SL8(s0, "0xC000"); SL8(s1, "0xC800"); SL8(s2, "0xD000"); SL8(s3, "0xD800");
    SL8(s4, "0xE000"); SL8(s5, "0xE800"); SL8(s6, "0xF000"); SL8(s7, "0xF800");
    SWAIT8();
    DOT8(s0, 24); DOT8(s1, 25); DOT8(s2, 26); DOT8(s3, 27);
    DOT8(s4, 28); DOT8(s5, 29); DOT8(s6, 30); DOT8(s7, 31);
  }

  float attn = -INFINITY;
#pragma unroll
  for (int m = 0; m < MQ; ++m) attn = fmaxf(attn, acc[m] * cinvG[j * MQ + m]);
  scoreG[(size_t)blk * NN + t] = s_imG[b * NN + t] + attn * ninvG[b * NN + t];
}

// ---------------- main per-(caption j, image b) kernel (post-score) ------
__global__ __launch_bounds__(256, 4) void k_main2(const float* __restrict__ img,
                                                  const float* __restrict__ cap,
                                                  const float* __restrict__ cinvG,
                                                  const float* __restrict__ scoreG,
                                                  const float* __restrict__ yG,
                                                  const float* __restrict__ scaleG,
                                                  float* __restrict__ out) {
  int blk = blockIdx.x;
  int b = blk / B_T, j = blk - b * B_T;
  int t = threadIdx.x, w = t >> 6, lane = t & 63;

  __shared__ float scoreL[NN];
  __shared__ int keepI[NKEEP];
  __shared__ int nonI[NKEEP];
  __shared__ float nonSc[NKEEP];
  __shared__ float nonW[NKEEP];
  __shared__ float cinvL[MQ];
  __shared__ float yL[NKEEP * 40];
  __shared__ float extraL[CC];
  __shared__ float c2t[MQ * 42];
  __shared__ float red[256], red2[256];
  __shared__ float rowM[MQ], colM[TOKS];
  __shared__ float sc0, sc1, sc2;

  if (t < MQ) cinvL[t] = cinvG[j * MQ + t];
  if (t < NN) scoreL[t] = scoreG[(size_t)blk * NN + t];
  __syncthreads();

  const float* capj = cap + (size_t)j * MQ * CC;

  if (t < NN) {
    float ms = scoreL[t];
    int rank = 0;
    for (int q = 0; q < NN; ++q) {
      float sq = scoreL[q];
      rank += (sq > ms) || (sq == ms && q < t);
    }
    if (rank < NKEEP) keepI[rank] = t;
    else { nonI[rank - NKEEP] = t; nonSc[rank - NKEEP] = ms; }
  }
  __syncthreads();

  float scaleV = scaleG[0];
  for (int p = t; p < NKEEP * 40; p += 256) {
    int i = p / 40, k = p - i * 40;
    yL[p] = (k < KEEPN) ? yG[(size_t)(b * NN + keepI[i]) * 40 + k] : 0.f;
  }
  if (t < 64) {
    float v0 = nonSc[t];
    float v1 = (t + 64 < NKEEP) ? nonSc[t + 64] : -INFINITY;
    float mx = waveMax(fmaxf(v0, v1));
    float e = expf(v0 - mx) + ((t + 64 < NKEEP) ? expf(v1 - mx) : 0.f);
    float s = waveSum(e);
    if (t == 0) { sc0 = mx; sc1 = s; }
  }
  __syncthreads();
  if (t < NKEEP) nonW[t] = expf(nonSc[t] - sc0) / sc1;
  if (t >= 128 && t < 128 + KEEPN) {
    int k = t - 128;
    float mx = -INFINITY;
    for (int i = 0; i < NKEEP; ++i) mx = fmaxf(mx, yL[i * 40 + k] * scaleV);
    float s = 0.f;
    for (int i = 0; i < NKEEP; ++i) {
      float e = expf(yL[i * 40 + k] * scaleV - mx);
      yL[i * 40 + k] = e;
      s += e;
    }
    float rs = 1.f / s;
    for (int i = 0; i < NKEEP; ++i) yL[i * 40 + k] *= rs;
  }
  __syncthreads();

  {
    int c0 = t, c1 = t + 256;
    float e0 = 0.f, e1 = 0.f;
    for (int i = 0; i < NKEEP; ++i) {
      int r = nonI[i];
      float wv = nonW[i];
      const float* row = img + ((size_t)b * 197 + 1 + r) * CC;
      e0 = fmaf(wv, row[c0], e0);
      e1 = fmaf(wv, row[c1], e1);
    }
    float cl0 = img[(size_t)b * 197 * CC + c0];
    float cl1 = img[(size_t)b * 197 * CC + c1];
    red[t] = e0 * e0 + e1 * e1;
    red2[t] = cl0 * cl0 + cl1 * cl1;
    __syncthreads();
    for (int s = 128; s > 0; s >>= 1) {
      if (t < s) { red[t] += red[t + s]; red2[t] += red2[t + s]; }
      __syncthreads();
    }
    if (t == 0) {
      red[0] = 1.f / fmaxf(sqrtf(red[0]), 1e-12f);
      sc2 = 1.f / fmaxf(sqrtf(red2[0]), 1e-12f);
    }
    __syncthreads();
    float rnE = red[0];
    extraL[c0] = e0 * rnE;
    extraL[c1] = e1 * rnE;
  }
  __syncthreads();

  {
    float acc[10][8];
#pragma unroll
    for (int q = 0; q < 10; ++q)
#pragma unroll
      for (int e = 0; e < 8; ++e) acc[q][e] = 0.f;
    for (int i = 0; i < NKEEP; ++i) {
      int r = keepI[i];
      const float* row = img + ((size_t)b * 197 + 1 + r) * CC + lane * 8;
      float4 s0 = *(const float4*)row;
      float4 s1 = *(const float4*)(row + 4);
      float sp8[8] = {s0.x, s0.y, s0.z, s0.w, s1.x, s1.y, s1.z, s1.w};
#pragma unroll
      for (int q = 0; q < 10; ++q) {
        int k = w + 4 * q;
        if (k < KEEPN) {
          float wv = yL[i * 40 + k];
#pragma unroll
          for (int e = 0; e < 8; ++e) acc[q][e] = fmaf(wv, sp8[e], acc[q][e]);
        }
      }
    }
#pragma unroll
    for (int q = 0; q < 10; ++q) {
      int k = w + 4 * q;
      if (k < KEEPN) {
        float ss = 0.f;
#pragma unroll
        for (int e = 0; e < 8; ++e) ss += acc[q][e] * acc[q][e];
        ss = waveSum(ss);
        float rn = 1.f / fmaxf(sqrtf(ss), 1e-12f);
#pragma unroll
        for (int e = 0; e < 8; ++e) acc[q][e] *= rn;
      }
    }
    for (int m = 0; m < MQ; ++m) {
      const float* cr = capj + m * CC + lane * 8;
      float4 c0 = *(const float4*)cr;
      float4 c1 = *(const float4*)(cr + 4);
      float cp8[8] = {c0.x, c0.y, c0.z, c0.w, c1.x, c1.y, c1.z, c1.w};
#pragma unroll
      for (int q = 0; q < 10; ++q) {
        int k = w + 4 * q;
        if (k < KEEPN) {
          float p = 0.f;
#pragma unroll
          for (int e = 0; e < 8; ++e) p = fmaf(acc[q][e], cp8[e], p);
          p = waveSum(p);
          if (lane == 0) c2t[m * 42 + 1 + k] = p * cinvL[m];
        }
      }
    }
  }

  {
    const float* clsrow = img + (size_t)b * 197 * CC + lane * 8;
    float4 a0 = *(const float4*)clsrow;
    float4 a1 = *(const float4*)(clsrow + 4);
    float cls8[8] = {a0.x, a0.y, a0.z, a0.w, a1.x, a1.y, a1.z, a1.w};
    float ex8[8];
#pragma unroll
    for (int e = 0; e < 8; ++e) ex8[e] = extraL[lane * 8 + e];
    float rnC = sc2;
    for (int mi = 0; mi < 8; ++mi) {
      int m = w * 8 + mi;
      const float* cr = capj + m * CC + lane * 8;
      float4 q0 = *(const float4*)cr;
      float4 q1 = *(const float4*)(cr + 4);
      float cp8[8] = {q0.x, q0.y, q0.z, q0.w, q1.x, q1.y, q1.z, q1.w};
      float pc = 0.f, pe = 0.f;
#pragma unroll
      for (int e = 0; e < 8; ++e) {
        pc = fmaf(cls8[e], cp8[e], pc);
        pe = fmaf(ex8[e], cp8[e], pe);
      }
      pc = waveSum(pc);
      pe = waveSum(pe);
      if (lane == 0) {
        c2t[m * 42 + 0] = pc * cinvL[m] * rnC;
        c2t[m * 42 + 40] = pe * cinvL[m];
      }
    }
  }
  __syncthreads();

  if (t < MQ) {
    float mx = -INFINITY;
    for (int tt = 0; tt < TOKS; ++tt) mx = fmaxf(mx, c2t[t * 42 + tt]);
    rowM[t] = (mx >= 0.f) ? mx : 0.1f * mx;
  } else if (t >= 64 && t < 64 + TOKS) {
    int tt = t - 64;
    float mx = -INFINITY;
    for (int m = 0; m < MQ; ++m) mx = fmaxf(mx, c2t[m * 42 + tt]);
    colM[tt] = (mx >= 0.f) ? mx : 0.1f * mx;
  }
  __syncthreads();
  if (t == 0) {
    float r = 0.f, c = 0.f;
    for (int m = 0; m < MQ; ++m) r += rowM[m];
    for (int tt = 0; tt < TOKS; ++tt) c += colM[tt];
    out[b * B_T + j] = r * (1.f / MQ) + c * (1.f / TOKS);
  }
}

extern "C" void kernel_launch(void* const* d_in, const int* in_sizes, int n_in,
                              void* d_out, int out_size, void* d_ws, size_t ws_size,
                              hipStream_t stream) {
  const float* img = (const float*)d_in[0];
  const float* cap = (const float*)d_in[1];
  const float* ln_g = (const float*)d_in[3];
  const float* ln_b = (const float*)d_in[4];
  const float* w1 = (const float*)d_in[5];
  const float* b1 = (const float*)d_in[6];
  const float* w2 = (const float*)d_in[7];
  const float* b2 = (const float*)d_in[8];
  const float* scale = (const float*)d_in[9];
  float* ws = (float*)d_ws;
  float* cinv = ws;                              // 48*32      = 1536
  float* ninv = ws + 1536;                       // 48*196     = 9408
  float* s_im = ws + 1536 + 9408;                // 48*196     = 9408
  float* y    = ws + 1536 + 9408 + 9408;         // 9408*40    = 376320
  float* scoreW = ws + 1536 + 9408 + 9408 + 376320;  // 2304*196 = 451584
  // mu/rs/w1gT/A/B live inside the scoreW region: consumed by k_gemm BEFORE
  // k_score overwrites scoreW (stream-ordered).
  float* muW   = scoreW;              // 9408
  float* rsW   = scoreW + 9408;       // 9408
  float* w1gT  = scoreW + 18816;      // 104*512 = 53248
  float* A     = scoreW + 72064;      // 104
  float* Bc    = scoreW + 72168;      // 104
  float* out = (float*)d_out;

  k_prep_img<<<B_V, 256, 0, stream>>>(img, ninv, s_im);
  k_prep_cap<<<B_T, 256, 0, stream>>>(cap, cinv);
  k_fold<<<104, 256, 0, stream>>>(w1, b1, ln_g, ln_b, w1gT, A, Bc);
  k_ln<<<2352, 256, 0, stream>>>(img, muW, rsW);
  k_gemm<<<147, 512, 0, stream>>>(img, w1gT, A, Bc, muW, rsW, w2, b2, y);
  k_score<<<B_V * B_T, 256, 0, stream>>>(img, cap, cinv, ninv, s_im, scoreW);
  k_main2<<<B_V * B_T, 256, 0, stream>>>(img, cap, cinv, scoreW, y, scale, out);
}